// Round 4
// baseline (901.841 us; speedup 1.0000x reference)
//
#include <hip/hip_runtime.h>

// Bag-level attention selector — wave-per-bag, branch-free CHUNK=8 online
// softmax with a preloaded 64-row label window.
//
//   repre:        (200000, 690) fp32   <- 552 MB, dominant HBM traffic
//   relation_mat: (53, 690) fp32
//   bias:         (53,) fp32
//   scope:        (25000, 2) int       (contiguous [start,end) per bag)
//   labels:       (200000,) int
//   out:          (25000, 53) fp32
//
// Round-3 post-mortem: branch-free chunking dropped the kernel below the
// harness fill kernels (<339 us/dispatch, from 440). Remaining serial chain
// per chunk was labels[row] -> rel-gather (2 dependent memory latencies).
// This version:
//   * preloads labels for a 64-row window with ONE coalesced lane-parallel
//     load; in-loop labels come from __shfl broadcast (register, 0 latency).
//     All rel-gather addresses become known upfront -> every memory op in
//     the bag loop is independent and pipelines.
//   * CHUNK=8 (divides the 64-row window exactly; chunks never straddle a
//     window, so shfl indices stay in [0,63]). 48 repre loads + 8 rel-dot
//     chains in flight per iteration; half the online-softmax steps.
//   * bags > 64 rows (P ~ e^-8, ~8 bags total) just reload the window.

#define NBAGS  25000
#define DDIM   690
#define D2     345      // float2 elements per row (rows are 8B-aligned)
#define RREL   53
#define WAVES  4
#define BLOCK  256      // 4 waves
#define CHUNK  8
#define WIN    64       // label window; WIN % CHUNK == 0
#define NEG_INF (-3.402823466e38f)

static __device__ __forceinline__ int imin(int a, int b) { return a < b ? a : b; }

__global__ __launch_bounds__(BLOCK, 3) void bag_attn_kernel(
    const float* __restrict__ repre,
    const float* __restrict__ rel,
    const float* __restrict__ bias,
    const int*   __restrict__ scope,
    const int*   __restrict__ labels,
    float*       __restrict__ out)
{
    __shared__ float s_att[WAVES * DDIM];   // 11 KB: 4 normalized att vectors

    const int tid  = threadIdx.x;
    const int lane = tid & 63;
    const int wave = tid >> 6;
    const int bag  = blockIdx.x * WAVES + wave;

    const int start = scope[2 * bag];
    const int end   = scope[2 * bag + 1];   // every bag has >= 1 row

    const float2* rel2 = (const float2*)rel;

    // Online-softmax state + lane-strided accumulator (f = lane + 64k, k<6)
    float2 acc[6];
    #pragma unroll
    for (int k = 0; k < 6; ++k) acc[k] = make_float2(0.f, 0.f);
    float m = NEG_INF;
    float l = 0.f;

    for (int w0 = start; w0 < end; w0 += WIN) {
        // One coalesced load covers labels for the whole 64-row window.
        const int labv = labels[imin(w0 + lane, end - 1)];
        const int wend = imin(w0 + WIN, end);

        for (int row = w0; row < wend; row += CHUNK) {
            const int nc = end - row;            // rows i < nc are real

            // --- 48 unconditional coalesced repre loads, all independent.
            float2 v[CHUNK][6];
            #pragma unroll
            for (int i = 0; i < CHUNK; ++i) {
                const int rc = imin(row + i, end - 1);
                const float2* rp = (const float2*)(repre + (size_t)rc * DDIM);
                #pragma unroll
                for (int k = 0; k < 6; ++k) {
                    const int f = lane + 64 * k;
                    v[i][k] = (f < D2) ? rp[f] : make_float2(0.f, 0.f);
                }
            }

            // --- 8 independent rel-gather dot chains; labels from registers
            //     (shfl broadcast), so all addresses are ready immediately.
            float dot[CHUNK];
            #pragma unroll
            for (int i = 0; i < CHUNK; ++i) {
                const int lab = __shfl(labv, row - w0 + i, 64); // uniform idx<=63
                const float2* rl = rel2 + (size_t)lab * D2;
                float d = 0.f;
                #pragma unroll
                for (int k = 0; k < 6; ++k) {
                    const int f = lane + 64 * k;
                    if (f < D2) {
                        const float2 u = rl[f];
                        d = fmaf(v[i][k].x, u.x, fmaf(v[i][k].y, u.y, d));
                    }
                }
                dot[i] = d;
            }

            // Interleaved cross-lane reductions: 8 independent shfl chains.
            #pragma unroll
            for (int o = 32; o; o >>= 1) {
                #pragma unroll
                for (int i = 0; i < CHUNK; ++i)
                    dot[i] += __shfl_xor(dot[i], o, 64);
            }

            // Neutralize padded rows AFTER the reduce: e_i = exp(-inf) = 0.
            #pragma unroll
            for (int i = 0; i < CHUNK; ++i)
                if (i >= nc) dot[i] = NEG_INF;   // i static, nc runtime -> cndmask

            // Block-wise online-softmax update (one rescale per chunk).
            float bm = dot[0];
            #pragma unroll
            for (int i = 1; i < CHUNK; ++i) bm = fmaxf(bm, dot[i]);
            const float nm = fmaxf(m, bm);       // finite: >= 1 active row
            const float sc = __expf(m - nm);     // first chunk: exp(-huge) = 0

            float e[CHUNK];
            float es = 0.f;
            #pragma unroll
            for (int i = 0; i < CHUNK; ++i) {
                e[i] = __expf(dot[i] - nm);      // padded rows contribute 0
                es  += e[i];
            }
            l = fmaf(l, sc, es);

            #pragma unroll
            for (int k = 0; k < 6; ++k) {
                float ax = acc[k].x * sc;
                float ay = acc[k].y * sc;
                #pragma unroll
                for (int i = 0; i < CHUNK; ++i) {
                    ax = fmaf(e[i], v[i][k].x, ax);
                    ay = fmaf(e[i], v[i][k].y, ay);
                }
                acc[k].x = ax;
                acc[k].y = ay;
            }
            m = nm;
        }
    }

    // Normalize and publish att vector to LDS
    const float inv = 1.f / l;
    float2* satt2 = (float2*)(s_att + wave * DDIM);
    #pragma unroll
    for (int k = 0; k < 6; ++k) {
        const int f = lane + 64 * k;
        if (f < D2) satt2[f] = make_float2(acc[k].x * inv, acc[k].y * inv);
    }
    __syncthreads();

    // Phase C: out[bag0+g, r] = dot(att[g], rel[r]) + bias[r]
    // Each rel row loaded once per block, dotted against all 4 att vectors.
    const int bag0 = blockIdx.x * WAVES;
    for (int r = wave; r < RREL; r += WAVES) {
        const float2* rl = rel2 + (size_t)r * D2;
        float2 u[6];
        #pragma unroll
        for (int k = 0; k < 6; ++k) {
            const int f = lane + 64 * k;
            u[k] = (f < D2) ? rl[f] : make_float2(0.f, 0.f);
        }
        const float b = bias[r];
        #pragma unroll
        for (int g = 0; g < WAVES; ++g) {
            const float2* a2 = (const float2*)(s_att + g * DDIM);
            float dot = 0.f;
            #pragma unroll
            for (int k = 0; k < 6; ++k) {
                const int f = lane + 64 * k;
                if (f < D2) {
                    const float2 a = a2[f];
                    dot = fmaf(u[k].x, a.x, fmaf(u[k].y, a.y, dot));
                }
            }
            #pragma unroll
            for (int o = 32; o; o >>= 1) dot += __shfl_xor(dot, o, 64);
            if (lane == 0) out[(size_t)(bag0 + g) * RREL + r] = dot + b;
        }
    }
}

extern "C" void kernel_launch(void* const* d_in, const int* in_sizes, int n_in,
                              void* d_out, int out_size, void* d_ws, size_t ws_size,
                              hipStream_t stream)
{
    const float* repre  = (const float*)d_in[0];
    const float* rel    = (const float*)d_in[1];
    const float* bias   = (const float*)d_in[2];
    const int*   scope  = (const int*)d_in[3];
    const int*   labels = (const int*)d_in[4];
    float*       out    = (float*)d_out;

    const int grid = NBAGS / WAVES;   // 6250, exact
    bag_attn_kernel<<<grid, BLOCK, 0, stream>>>(repre, rel, bias, scope, labels, out);
}